// Round 1
// baseline (195.785 us; speedup 1.0000x reference)
//
#include <hip/hip_runtime.h>

// OIntInferMatMul: y = clip(round( (clip(round(x1*r1)) @ clip(round(x2*r2))) / 16 ), -128, 127)
// x1: [32, 2048, 64] fp32 (integer-valued), x2: [32, 64, 2048] fp32 -> out [32, 2048, 2048] fp32.
// Strategy: quantize to int8 in registers, one mfma_i32_16x16x64_i8 per 16x16 fragment (K=64
// exactly one MFMA deep -> no K loop, no LDS). Write-BW bound (~512 MiB out).

typedef int   v4i __attribute__((ext_vector_type(4)));
typedef float v4f __attribute__((ext_vector_type(4)));

static constexpr int BATCH = 32;     // 2*16 fused batch-heads
static constexpr int SEQ   = 2048;
static constexpr int DIM   = 64;
static constexpr int TILE  = 128;    // 128x128 output tile per block
static constexpr int TPB   = 256;    // 4 waves, 2x2 wave grid (each wave 64x64)
static constexpr int TPS   = SEQ / TILE;          // 16 tiles per side
static constexpr int TPBATCH = TPS * TPS;         // 256 tiles per batch
static constexpr int NBLK  = BATCH * TPBATCH;     // 8192 blocks

__global__ __launch_bounds__(TPB) void oint_mm_kernel(
    const float* __restrict__ x1,
    const float* __restrict__ x2,
    const float* __restrict__ p_s1ll,
    const float* __restrict__ p_sx1,
    const float* __restrict__ p_s2ll,
    const float* __restrict__ p_sx2,
    float* __restrict__ out)
{
    const float r1 = p_s1ll[0] / p_sx1[0];
    const float r2 = p_s2ll[0] / p_sx2[0];

    // Bijective XCD-aware swizzle (NBLK % 8 == 0): each XCD gets 4 whole batches
    // -> per-XCD L2 working set = 4 x 1 MiB of inputs.
    const int bid     = (int)blockIdx.x;
    const int logical = (bid & 7) * (NBLK >> 3) + (bid >> 3);

    const int batch = logical >> 8;                 // / TPBATCH
    const int t     = logical & (TPBATCH - 1);
    const int tm    = t >> 4;
    const int tn    = t & (TPS - 1);

    const float* Abase = x1 + (size_t)batch * SEQ * DIM;
    const float* Bbase = x2 + (size_t)batch * DIM * SEQ;
    float*       Obase = out + (size_t)batch * SEQ * SEQ;

    const int tid  = (int)threadIdx.x;
    const int lane = tid & 63;
    const int wave = tid >> 6;
    const int wr   = wave >> 1;
    const int wc   = wave & 1;

    const int mbase = tm * TILE + wr * 64;
    const int nbase = tn * TILE + wc * 64;

    const int lr = lane & 15;   // row (A) / col (B,D) within 16x16 fragment
    const int kq = lane >> 4;   // k-quadrant: 16 consecutive k per lane
    const int k0 = kq * 16;

    // ---- A fragments: lane holds A[m][k0..k0+15] quantized to 16 x i8 ----
    v4i afrag[4];
    #pragma unroll
    for (int fm = 0; fm < 4; ++fm) {
        const float* src = Abase + (mbase + fm * 16 + lr) * DIM + k0;
        v4i pk;
        #pragma unroll
        for (int d = 0; d < 4; ++d) {
            v4f v = *(const v4f*)(src + 4 * d);
            int dw = 0;
            #pragma unroll
            for (int j = 0; j < 4; ++j) {
                float q = rintf(v[j] * r1);          // round half-even == jnp.round
                q = fminf(fmaxf(q, -128.f), 127.f);  // clip
                dw |= ((int)q & 0xFF) << (8 * j);    // byte b = k0+4d+j (little-endian k)
            }
            pk[d] = dw;
        }
        afrag[fm] = pk;
    }

    // ---- B fragments: lane holds B[k0..k0+15][n] (n = col), strided loads ----
    // Lanes 0..15 read consecutive n -> each load instr = 4 dense 64B segments (L2-hot).
    v4i bfrag[4];
    #pragma unroll
    for (int fn = 0; fn < 4; ++fn) {
        const float* src = Bbase + (size_t)k0 * SEQ + (nbase + fn * 16 + lr);
        v4i pk;
        #pragma unroll
        for (int d = 0; d < 4; ++d) {
            int dw = 0;
            #pragma unroll
            for (int j = 0; j < 4; ++j) {
                float q = rintf(src[(size_t)(4 * d + j) * SEQ] * r2);
                q = fminf(fmaxf(q, -128.f), 127.f);
                dw |= ((int)q & 0xFF) << (8 * j);
            }
            pk[d] = dw;
        }
        bfrag[fn] = pk;
    }

    // ---- 16 independent MFMAs: full K=64 in one instruction each ----
    v4i acc[4][4];
    #pragma unroll
    for (int fm = 0; fm < 4; ++fm) {
        #pragma unroll
        for (int fn = 0; fn < 4; ++fn) {
            v4i z = {0, 0, 0, 0};
            acc[fm][fn] = __builtin_amdgcn_mfma_i32_16x16x64_i8(afrag[fm], bfrag[fn], z, 0, 0, 0);
        }
    }

    // ---- Epilogue: D layout col = lane&15, row = (lane>>4)*4 + reg (measured m89) ----
    // acc <= 64*128*128 = 2^20 -> exact in fp32; /16 exact; rintf = jnp.round.
    #pragma unroll
    for (int fm = 0; fm < 4; ++fm) {
        #pragma unroll
        for (int r = 0; r < 4; ++r) {
            const int m = mbase + fm * 16 + kq * 4 + r;
            float* orow = Obase + (size_t)m * SEQ + nbase + lr;
            #pragma unroll
            for (int fn = 0; fn < 4; ++fn) {
                float v = rintf((float)acc[fm][fn][r] * 0.0625f);
                v = fminf(fmaxf(v, -128.f), 127.f);
                orow[fn * 16] = v;   // lanes 0..15 -> 64B dense per row-quarter
            }
        }
    }
}

extern "C" void kernel_launch(void* const* d_in, const int* in_sizes, int n_in,
                              void* d_out, int out_size, void* d_ws, size_t ws_size,
                              hipStream_t stream) {
    (void)in_sizes; (void)n_in; (void)out_size; (void)d_ws; (void)ws_size;
    oint_mm_kernel<<<NBLK, TPB, 0, stream>>>(
        (const float*)d_in[0], (const float*)d_in[1],
        (const float*)d_in[2], (const float*)d_in[3],
        (const float*)d_in[4], (const float*)d_in[5],
        (float*)d_out);
}

// Round 2
// 108.760 us; speedup vs baseline: 1.8002x; 1.8002x over previous
//
#include <hip/hip_runtime.h>

// OIntInferMatMul: y = clip(round( (clip(round(x1*r1)) @ clip(round(x2*r2))) / 16 ), -128, 127)
// x1: [32, 2048, 64] fp32 (integer-valued), x2: [32, 64, 2048] fp32 -> out [32, 2048, 2048] fp32.
// Round 2: 32x32x32 i8 MFMA (full 128B store lines), per-fm acc split (VGPR), nontemporal stores.

typedef int   v4i  __attribute__((ext_vector_type(4)));
typedef int   v16i __attribute__((ext_vector_type(16)));
typedef float v4f  __attribute__((ext_vector_type(4)));

static constexpr int BATCH = 32;     // 2*16 fused batch-heads
static constexpr int SEQ   = 2048;
static constexpr int DIM   = 64;
static constexpr int TILE  = 128;    // 128x128 output tile per block
static constexpr int TPB   = 256;    // 4 waves, 2x2; each wave owns 64x64 = 2x2 frags of 32x32
static constexpr int TPS   = SEQ / TILE;          // 16
static constexpr int TPBATCH = TPS * TPS;         // 256
static constexpr int NBLK  = BATCH * TPBATCH;     // 8192

__global__ __launch_bounds__(TPB) void oint_mm_kernel(
    const float* __restrict__ x1,
    const float* __restrict__ x2,
    const float* __restrict__ p_s1ll,
    const float* __restrict__ p_sx1,
    const float* __restrict__ p_s2ll,
    const float* __restrict__ p_sx2,
    float* __restrict__ out)
{
    const float r1 = p_s1ll[0] / p_sx1[0];
    const float r2 = p_s2ll[0] / p_sx2[0];

    // Bijective XCD swizzle (NBLK % 8 == 0): 4 whole batches per XCD -> L2-local inputs.
    const int bid     = (int)blockIdx.x;
    const int logical = (bid & 7) * (NBLK >> 3) + (bid >> 3);

    const int batch = logical >> 8;
    const int t     = logical & (TPBATCH - 1);
    const int tm    = t >> 4;
    const int tn    = t & (TPS - 1);

    const float* Abase = x1 + (size_t)batch * SEQ * DIM;
    const float* Bbase = x2 + (size_t)batch * DIM * SEQ;
    float*       Obase = out + (size_t)batch * SEQ * SEQ;

    const int tid  = (int)threadIdx.x;
    const int lane = tid & 63;
    const int wave = tid >> 6;
    const int wr   = wave >> 1;
    const int wc   = wave & 1;

    const int mbase = tm * TILE + wr * 64;
    const int nbase = tn * TILE + wc * 64;

    const int lc = lane & 31;   // row (A) / col (B, D) within 32x32 fragment
    const int kh = lane >> 5;   // k-half: 16 consecutive k-bytes per lane per MFMA step

    // ---- B fragments: bfrag[fn][step], lane holds B[s*32+kh*16 .. +15][col] ----
    v4i bfrag[2][2];
    #pragma unroll
    for (int fn = 0; fn < 2; ++fn) {
        #pragma unroll
        for (int s = 0; s < 2; ++s) {
            const float* src = Bbase + (size_t)(s * 32 + kh * 16) * SEQ + (nbase + fn * 32 + lc);
            v4i pk;
            #pragma unroll
            for (int d = 0; d < 4; ++d) {
                int dw = 0;
                #pragma unroll
                for (int j = 0; j < 4; ++j) {
                    float q = rintf(src[(size_t)(4 * d + j) * SEQ] * r2);  // half-even == jnp.round
                    q = fminf(fmaxf(q, -128.f), 127.f);
                    dw |= ((int)q & 0xFF) << (8 * j);
                }
                pk[d] = dw;
            }
            bfrag[fn][s] = pk;
        }
    }

    // ---- per-fm: load A frags, 2 chained MFMAs per fn, immediate epilogue ----
    #pragma unroll
    for (int fm = 0; fm < 2; ++fm) {
        v4i af[2];
        #pragma unroll
        for (int s = 0; s < 2; ++s) {
            const float* src = Abase + (size_t)(mbase + fm * 32 + lc) * DIM + s * 32 + kh * 16;
            v4i pk;
            #pragma unroll
            for (int d = 0; d < 4; ++d) {
                v4f v = *(const v4f*)(src + 4 * d);
                int dw = 0;
                #pragma unroll
                for (int j = 0; j < 4; ++j) {
                    float q = rintf(v[j] * r1);
                    q = fminf(fmaxf(q, -128.f), 127.f);
                    dw |= ((int)q & 0xFF) << (8 * j);
                }
                pk[d] = dw;
            }
            af[s] = pk;
        }

        #pragma unroll
        for (int fn = 0; fn < 2; ++fn) {
            v16i z = {0,0,0,0,0,0,0,0,0,0,0,0,0,0,0,0};
            v16i acc = __builtin_amdgcn_mfma_i32_32x32x32_i8(af[0], bfrag[fn][0], z,   0, 0, 0);
            acc      = __builtin_amdgcn_mfma_i32_32x32x32_i8(af[1], bfrag[fn][1], acc, 0, 0, 0);

            // D layout (32x32): col = lane&31, row = (r&3) + 8*(r>>2) + 4*kh.
            // Fixed r -> lanes write 2 full 128B lines (32 contiguous floats x 2 rows).
            #pragma unroll
            for (int r = 0; r < 16; ++r) {
                const int m = mbase + fm * 32 + (r & 3) + 8 * (r >> 2) + 4 * kh;
                float v = rintf((float)acc[r] * 0.0625f);   // exact: |acc| <= 2^20
                v = fminf(fmaxf(v, -128.f), 127.f);
                __builtin_nontemporal_store(v, Obase + (size_t)m * SEQ + nbase + fn * 32 + lc);
            }
        }
    }
}

extern "C" void kernel_launch(void* const* d_in, const int* in_sizes, int n_in,
                              void* d_out, int out_size, void* d_ws, size_t ws_size,
                              hipStream_t stream) {
    (void)in_sizes; (void)n_in; (void)out_size; (void)d_ws; (void)ws_size;
    oint_mm_kernel<<<NBLK, TPB, 0, stream>>>(
        (const float*)d_in[0], (const float*)d_in[1],
        (const float*)d_in[2], (const float*)d_in[3],
        (const float*)d_in[4], (const float*)d_in[5],
        (float*)d_out);
}

// Round 3
// 106.061 us; speedup vs baseline: 1.8460x; 1.0254x over previous
//
#include <hip/hip_runtime.h>

// OIntInferMatMul: y = clip(round( (clip(round(x1*r1)) @ clip(round(x2*r2))) / 16 ), -128, 127)
// x1: [32, 2048, 64] fp32 (integer-valued), x2: [32, 64, 2048] fp32 -> out [32, 2048, 2048] fp32.
// Round 3: LDS-transposed epilogue -> dwordx4 nontemporal stores (full-line 1KB bursts),
// replacing 64 scattered 4B/lane stores per thread with 16 float4 stores.

typedef int   v4i  __attribute__((ext_vector_type(4)));
typedef int   v16i __attribute__((ext_vector_type(16)));
typedef float v4f  __attribute__((ext_vector_type(4)));

static constexpr int BATCH = 32;     // 2*16 fused batch-heads
static constexpr int SEQ   = 2048;
static constexpr int DIM   = 64;
static constexpr int TILE  = 128;    // 128x128 output tile per block
static constexpr int TPB   = 256;    // 4 waves, 2x2; each wave owns 64x64
static constexpr int TPS   = SEQ / TILE;          // 16
static constexpr int TPBATCH = TPS * TPS;         // 256
static constexpr int NBLK  = BATCH * TPBATCH;     // 8192

__global__ __launch_bounds__(TPB) void oint_mm_kernel(
    const float* __restrict__ x1,
    const float* __restrict__ x2,
    const float* __restrict__ p_s1ll,
    const float* __restrict__ p_sx1,
    const float* __restrict__ p_s2ll,
    const float* __restrict__ p_sx2,
    float* __restrict__ out)
{
    __shared__ float slab[64 * 128];   // 32 KiB epilogue transpose buffer

    const float r1 = p_s1ll[0] / p_sx1[0];
    const float r2 = p_s2ll[0] / p_sx2[0];

    // Bijective XCD swizzle (NBLK % 8 == 0): 4 whole batches per XCD -> L2-local inputs.
    const int bid     = (int)blockIdx.x;
    const int logical = (bid & 7) * (NBLK >> 3) + (bid >> 3);

    const int batch = logical >> 8;
    const int t     = logical & (TPBATCH - 1);
    const int tm    = t >> 4;
    const int tn    = t & (TPS - 1);

    const float* Abase = x1 + (size_t)batch * SEQ * DIM;
    const float* Bbase = x2 + (size_t)batch * DIM * SEQ;
    float*       Obase = out + (size_t)batch * SEQ * SEQ;

    const int tid  = (int)threadIdx.x;
    const int lane = tid & 63;
    const int wave = tid >> 6;
    const int wr   = wave >> 1;
    const int wc   = wave & 1;

    const int mbase = tm * TILE + wr * 64;
    const int nbase = tn * TILE + wc * 64;

    const int lc = lane & 31;   // row (A) / col (B, D) within 32x32 fragment
    const int kh = lane >> 5;   // k-half: 16 consecutive k-bytes per lane per MFMA step

    // ---- B fragments: bfrag[fn][step], lane holds B[s*32+kh*16 .. +15][col] ----
    v4i bfrag[2][2];
    #pragma unroll
    for (int fn = 0; fn < 2; ++fn) {
        #pragma unroll
        for (int s = 0; s < 2; ++s) {
            const float* src = Bbase + (size_t)(s * 32 + kh * 16) * SEQ + (nbase + fn * 32 + lc);
            v4i pk;
            #pragma unroll
            for (int d = 0; d < 4; ++d) {
                int dw = 0;
                #pragma unroll
                for (int j = 0; j < 4; ++j) {
                    float q = rintf(src[(size_t)(4 * d + j) * SEQ] * r2);  // half-even == jnp.round
                    q = fminf(fmaxf(q, -128.f), 127.f);
                    dw |= ((int)q & 0xFF) << (8 * j);
                }
                pk[d] = dw;
            }
            bfrag[fn][s] = pk;
        }
    }

    #pragma unroll
    for (int fm = 0; fm < 2; ++fm) {
        if (fm) __syncthreads();   // slab reuse guard between phases

        // ---- A fragments for this 32-row slice ----
        v4i af[2];
        #pragma unroll
        for (int s = 0; s < 2; ++s) {
            const float* src = Abase + (size_t)(mbase + fm * 32 + lc) * DIM + s * 32 + kh * 16;
            v4i pk;
            #pragma unroll
            for (int d = 0; d < 4; ++d) {
                v4f v = *(const v4f*)(src + 4 * d);
                int dw = 0;
                #pragma unroll
                for (int j = 0; j < 4; ++j) {
                    float q = rintf(v[j] * r1);
                    q = fminf(fmaxf(q, -128.f), 127.f);
                    dw |= ((int)q & 0xFF) << (8 * j);
                }
                pk[d] = dw;
            }
            af[s] = pk;
        }

        // ---- MFMA + epilogue math -> LDS slab (64 rows x 128 cols fp32) ----
        #pragma unroll
        for (int fn = 0; fn < 2; ++fn) {
            v16i z = {0,0,0,0,0,0,0,0,0,0,0,0,0,0,0,0};
            v16i acc = __builtin_amdgcn_mfma_i32_32x32x32_i8(af[0], bfrag[fn][0], z,   0, 0, 0);
            acc      = __builtin_amdgcn_mfma_i32_32x32x32_i8(af[1], bfrag[fn][1], acc, 0, 0, 0);

            // D layout (32x32): col = lane&31, row = (r&3) + 8*(r>>2) + 4*kh.
            #pragma unroll
            for (int r = 0; r < 16; ++r) {
                const int rloc = (r & 3) + 8 * (r >> 2) + 4 * kh;      // [0,32)
                const int sr   = wr * 32 + rloc;                       // slab row
                const int c    = wc * 64 + fn * 32 + lc;               // slab col
                float v = rintf((float)acc[r] * 0.0625f);   // exact: |acc| <= 2^20
                v = fminf(fmaxf(v, -128.f), 127.f);
                slab[sr * 128 + c] = v;   // banks = c%32 -> 2-way alias only (free)
            }
        }

        __syncthreads();

        // ---- Cooperative store: slab row sr -> global row; float4 NT stores ----
        // slab row sr covers global row tm*128 + (sr>>5)*64 + fm*32 + (sr&31).
        #pragma unroll
        for (int i = 0; i < 8; ++i) {
            const int f  = i * TPB + tid;          // [0, 2048) float4 index
            const int sr = f >> 5;
            const int cq = f & 31;
            v4f v = *(const v4f*)&slab[sr * 128 + cq * 4];
            const int grow = tm * TILE + ((sr >> 5) << 6) + fm * 32 + (sr & 31);
            __builtin_nontemporal_store(
                v, (v4f*)(Obase + (size_t)grow * SEQ + tn * TILE + cq * 4));
        }
    }
}

extern "C" void kernel_launch(void* const* d_in, const int* in_sizes, int n_in,
                              void* d_out, int out_size, void* d_ws, size_t ws_size,
                              hipStream_t stream) {
    (void)in_sizes; (void)n_in; (void)out_size; (void)d_ws; (void)ws_size;
    oint_mm_kernel<<<NBLK, TPB, 0, stream>>>(
        (const float*)d_in[0], (const float*)d_in[1],
        (const float*)d_in[2], (const float*)d_in[3],
        (const float*)d_in[4], (const float*)d_in[5],
        (float*)d_out);
}

// Round 4
// 100.434 us; speedup vs baseline: 1.9494x; 1.0560x over previous
//
#include <hip/hip_runtime.h>

// OIntInferMatMul: y = clip(round( (clip(round(x1*r1)) @ clip(round(x2*r2))) / 16 ), -128, 127)
// x1: [32, 2048, 64] fp32 (integer-valued), x2: [32, 64, 2048] fp32 -> out [32, 2048, 2048] fp32.
// Round 4: two-pass. prepack quantizes x1/x2 -> int8 ONCE (vs 16x redundant in fused kernel)
// into k-chunk-major layouts; main kernel is 8 dwordx4 loads + 4 MFMAs + store burst.

typedef int   v4i  __attribute__((ext_vector_type(4)));
typedef int   v16i __attribute__((ext_vector_type(16)));
typedef float v4f  __attribute__((ext_vector_type(4)));

static constexpr int BATCH = 32;     // 2*16 fused batch-heads
static constexpr int SEQ   = 2048;
static constexpr int DIM   = 64;
static constexpr int TILE  = 128;
static constexpr int TPB   = 256;    // 4 waves, 2x2; each wave owns 64x64
static constexpr int TPS   = SEQ / TILE;          // 16
static constexpr int TPBATCH = TPS * TPS;         // 256
static constexpr int NBLK  = BATCH * TPBATCH;     // 8192
static constexpr size_t PKB = (size_t)BATCH * SEQ * DIM;   // 4 MiB per packed operand

__device__ __forceinline__ int qpack4(v4f v, float r) {
    int dw = 0;
    #pragma unroll
    for (int j = 0; j < 4; ++j) {
        float q = rintf(v[j] * r);           // round half-even == jnp.round
        q = fminf(fmaxf(q, -128.f), 127.f);  // clip
        dw |= ((int)q & 0xFF) << (8 * j);
    }
    return dw;
}

// A8 layout: [b][kq][m][16B], kq = k/16.  B8 layout: [b][kq][n][16B].
__global__ __launch_bounds__(256) void prepack_kernel(
    const float* __restrict__ x1, const float* __restrict__ x2,
    const float* __restrict__ p_s1ll, const float* __restrict__ p_sx1,
    const float* __restrict__ p_s2ll, const float* __restrict__ p_sx2,
    char* __restrict__ A8, char* __restrict__ B8)
{
    const int bid = (int)blockIdx.x;
    const int tid = (int)threadIdx.x;
    if (bid < 1024) {
        // ---- x1 -> A8. Reads perfectly contiguous; writes in dense 256B chunks. ----
        const float r1 = p_s1ll[0] / p_sx1[0];
        const int t  = bid * 256 + tid;          // [0, 256K)
        const int b  = t >> 13;
        const int m  = (t >> 2) & 2047;
        const int kq = t & 3;
        const float* src = x1 + (size_t)t * 16;  // == ((b*2048+m)*4+kq)*16
        v4i pk;
        #pragma unroll
        for (int d = 0; d < 4; ++d) pk[d] = qpack4(*(const v4f*)(src + 4 * d), r1);
        *(v4i*)(A8 + ((size_t)(b * 4 + kq) * SEQ + m) * 16) = pk;
    } else {
        // ---- x2 -> B8 (transpose-pack). Reads 256B-coalesced; writes contiguous. ----
        const float r2 = p_s2ll[0] / p_sx2[0];
        const int t  = (bid - 1024) * 256 + tid; // [0, 256K)
        const int b  = t >> 13;
        const int kq = (t >> 11) & 3;
        const int n  = t & 2047;
        const float* src = x2 + (size_t)b * DIM * SEQ + (size_t)(kq * 16) * SEQ + n;
        v4i pk;
        #pragma unroll
        for (int d = 0; d < 4; ++d) {
            int dw = 0;
            #pragma unroll
            for (int j = 0; j < 4; ++j) {
                float q = rintf(src[(size_t)(4 * d + j) * SEQ] * r2);
                q = fminf(fmaxf(q, -128.f), 127.f);
                dw |= ((int)q & 0xFF) << (8 * j);
            }
            pk[d] = dw;
        }
        *(v4i*)(B8 + (size_t)t * 16) = pk;       // flat index == ((b*4+kq)*SEQ+n)
    }
}

__global__ __launch_bounds__(TPB) void oint_mm_packed(
    const char* __restrict__ A8, const char* __restrict__ B8,
    float* __restrict__ out)
{
    __shared__ float slab[64 * 128];   // 32 KiB epilogue transpose buffer

    const int bid     = (int)blockIdx.x;
    const int logical = (bid & 7) * (NBLK >> 3) + (bid >> 3);   // bijective XCD swizzle

    const int batch = logical >> 8;
    const int t     = logical & (TPBATCH - 1);
    const int tm    = t >> 4;
    const int tn    = t & (TPS - 1);

    float* Obase = out + (size_t)batch * SEQ * SEQ;

    const int tid  = (int)threadIdx.x;
    const int lane = tid & 63;
    const int wave = tid >> 6;
    const int wr   = wave >> 1;
    const int wc   = wave & 1;

    const int mbase = tm * TILE + wr * 64;
    const int nbase = tn * TILE + wc * 64;

    const int lc = lane & 31;   // row (A) / col (B, D) within 32x32 fragment
    const int kh = lane >> 5;   // k-half within a 32-wide MFMA step

    // ---- B fragments: one dwordx4 each, wave-contiguous (lanes 0-31 read 512B dense) ----
    v4i bfrag[2][2];
    #pragma unroll
    for (int fn = 0; fn < 2; ++fn)
        #pragma unroll
        for (int s = 0; s < 2; ++s)
            bfrag[fn][s] = *(const v4i*)(
                B8 + ((size_t)(batch * 4 + s * 2 + kh) * SEQ + nbase + fn * 32 + lc) * 16);

    #pragma unroll
    for (int fm = 0; fm < 2; ++fm) {
        if (fm) __syncthreads();   // slab reuse guard between phases

        v4i af[2];
        #pragma unroll
        for (int s = 0; s < 2; ++s)
            af[s] = *(const v4i*)(
                A8 + ((size_t)(batch * 4 + s * 2 + kh) * SEQ + mbase + fm * 32 + lc) * 16);

        #pragma unroll
        for (int fn = 0; fn < 2; ++fn) {
            v16i z = {0,0,0,0,0,0,0,0,0,0,0,0,0,0,0,0};
            v16i acc = __builtin_amdgcn_mfma_i32_32x32x32_i8(af[0], bfrag[fn][0], z,   0, 0, 0);
            acc      = __builtin_amdgcn_mfma_i32_32x32x32_i8(af[1], bfrag[fn][1], acc, 0, 0, 0);

            // D layout (32x32): col = lane&31, row = (r&3) + 8*(r>>2) + 4*kh.
            #pragma unroll
            for (int r = 0; r < 16; ++r) {
                const int rloc = (r & 3) + 8 * (r >> 2) + 4 * kh;
                const int sr   = wr * 32 + rloc;
                const int c    = wc * 64 + fn * 32 + lc;
                float v = rintf((float)acc[r] * 0.0625f);   // exact: |acc| <= 2^20
                v = fminf(fmaxf(v, -128.f), 127.f);
                slab[sr * 128 + c] = v;   // 2-way bank alias only (free)
            }
        }

        __syncthreads();

        // ---- Cooperative store: float4 NT, full 128B lines, 1KB per wave-instr ----
        #pragma unroll
        for (int i = 0; i < 8; ++i) {
            const int f  = i * TPB + tid;
            const int sr = f >> 5;
            const int cq = f & 31;
            v4f v = *(const v4f*)&slab[sr * 128 + cq * 4];
            const int grow = tm * TILE + ((sr >> 5) << 6) + fm * 32 + (sr & 31);
            __builtin_nontemporal_store(
                v, (v4f*)(Obase + (size_t)grow * SEQ + tn * TILE + cq * 4));
        }
    }
}

// ---- Fallback (round-3 fused kernel) if d_ws is too small for packed operands ----
__global__ __launch_bounds__(TPB) void oint_mm_fused(
    const float* __restrict__ x1, const float* __restrict__ x2,
    const float* __restrict__ p_s1ll, const float* __restrict__ p_sx1,
    const float* __restrict__ p_s2ll, const float* __restrict__ p_sx2,
    float* __restrict__ out)
{
    __shared__ float slab[64 * 128];
    const float r1 = p_s1ll[0] / p_sx1[0];
    const float r2 = p_s2ll[0] / p_sx2[0];
    const int bid     = (int)blockIdx.x;
    const int logical = (bid & 7) * (NBLK >> 3) + (bid >> 3);
    const int batch = logical >> 8;
    const int t     = logical & (TPBATCH - 1);
    const int tm    = t >> 4;
    const int tn    = t & (TPS - 1);
    const float* Abase = x1 + (size_t)batch * SEQ * DIM;
    const float* Bbase = x2 + (size_t)batch * DIM * SEQ;
    float*       Obase = out + (size_t)batch * SEQ * SEQ;
    const int tid  = (int)threadIdx.x;
    const int lane = tid & 63;
    const int wave = tid >> 6;
    const int wr   = wave >> 1;
    const int wc   = wave & 1;
    const int mbase = tm * TILE + wr * 64;
    const int nbase = tn * TILE + wc * 64;
    const int lc = lane & 31;
    const int kh = lane >> 5;

    v4i bfrag[2][2];
    #pragma unroll
    for (int fn = 0; fn < 2; ++fn) {
        #pragma unroll
        for (int s = 0; s < 2; ++s) {
            const float* src = Bbase + (size_t)(s * 32 + kh * 16) * SEQ + (nbase + fn * 32 + lc);
            v4i pk;
            #pragma unroll
            for (int d = 0; d < 4; ++d) {
                int dw = 0;
                #pragma unroll
                for (int j = 0; j < 4; ++j) {
                    float q = rintf(src[(size_t)(4 * d + j) * SEQ] * r2);
                    q = fminf(fmaxf(q, -128.f), 127.f);
                    dw |= ((int)q & 0xFF) << (8 * j);
                }
                pk[d] = dw;
            }
            bfrag[fn][s] = pk;
        }
    }
    #pragma unroll
    for (int fm = 0; fm < 2; ++fm) {
        if (fm) __syncthreads();
        v4i af[2];
        #pragma unroll
        for (int s = 0; s < 2; ++s) {
            const float* src = Abase + (size_t)(mbase + fm * 32 + lc) * DIM + s * 32 + kh * 16;
            v4i pk;
            #pragma unroll
            for (int d = 0; d < 4; ++d) pk[d] = qpack4(*(const v4f*)(src + 4 * d), r1);
            af[s] = pk;
        }
        #pragma unroll
        for (int fn = 0; fn < 2; ++fn) {
            v16i z = {0,0,0,0,0,0,0,0,0,0,0,0,0,0,0,0};
            v16i acc = __builtin_amdgcn_mfma_i32_32x32x32_i8(af[0], bfrag[fn][0], z,   0, 0, 0);
            acc      = __builtin_amdgcn_mfma_i32_32x32x32_i8(af[1], bfrag[fn][1], acc, 0, 0, 0);
            #pragma unroll
            for (int r = 0; r < 16; ++r) {
                const int rloc = (r & 3) + 8 * (r >> 2) + 4 * kh;
                const int sr   = wr * 32 + rloc;
                const int c    = wc * 64 + fn * 32 + lc;
                float v = rintf((float)acc[r] * 0.0625f);
                v = fminf(fmaxf(v, -128.f), 127.f);
                slab[sr * 128 + c] = v;
            }
        }
        __syncthreads();
        #pragma unroll
        for (int i = 0; i < 8; ++i) {
            const int f  = i * TPB + tid;
            const int sr = f >> 5;
            const int cq = f & 31;
            v4f v = *(const v4f*)&slab[sr * 128 + cq * 4];
            const int grow = tm * TILE + ((sr >> 5) << 6) + fm * 32 + (sr & 31);
            __builtin_nontemporal_store(
                v, (v4f*)(Obase + (size_t)grow * SEQ + tn * TILE + cq * 4));
        }
    }
}

extern "C" void kernel_launch(void* const* d_in, const int* in_sizes, int n_in,
                              void* d_out, int out_size, void* d_ws, size_t ws_size,
                              hipStream_t stream) {
    (void)in_sizes; (void)n_in; (void)out_size;
    const float* x1 = (const float*)d_in[0];
    const float* x2 = (const float*)d_in[1];
    const float* s1 = (const float*)d_in[2];
    const float* s2 = (const float*)d_in[3];
    const float* s3 = (const float*)d_in[4];
    const float* s4 = (const float*)d_in[5];
    float* out = (float*)d_out;

    if (ws_size >= 2 * PKB) {
        char* A8 = (char*)d_ws;
        char* B8 = (char*)d_ws + PKB;
        prepack_kernel<<<2048, 256, 0, stream>>>(x1, x2, s1, s2, s3, s4, A8, B8);
        oint_mm_packed<<<NBLK, TPB, 0, stream>>>(A8, B8, out);
    } else {
        oint_mm_fused<<<NBLK, TPB, 0, stream>>>(x1, x2, s1, s2, s3, s4, out);
    }
}